// Round 1
// baseline (1170.860 us; speedup 1.0000x reference)
//
#include <hip/hip_runtime.h>
#include <hip/hip_bf16.h>

// WindowAttention3D: B=2048 windows, N=98, C=128, H=4, hd=32, mask windows=256.
// Baseline round 0: fp32 vector math, bf16 staging/intermediates.
//   k0: bias[h][n][m] precompute
//   k1: qkv = x@W^T+b  -> q*scale,k,v bf16 [b][h][98][32] in ws
//   k2: per (b,h): scores(98x98)+bias+mask, softmax, @v -> o bf16 [b][98][128]
//   k3: out = o@proj_w^T + proj_b (fp32)
// ws bytes: 4*25690112*2 + 153664 = 205,674,560

#define NTOK 98
#define HEADS 4
#define HD 32
#define NN (NTOK * NTOK)
#define SCALE 0.17677669529663687f

#define TR 32
#define XPAD 36   // 32 rows + pad (transposed x/o tile), 72B row stride (8B aligned)
#define WPAD 132  // 128 cols + pad (transposed w tile), 264B row stride (8B aligned)
#define QPAD 34   // 32 + pad for q/k/v rows in k2

static __device__ __forceinline__ float lo2f(unsigned int u) {
  union { unsigned int i; float f; } x; x.i = u << 16; return x.f;
}
static __device__ __forceinline__ float hi2f(unsigned int u) {
  union { unsigned int i; float f; } x; x.i = u & 0xffff0000u; return x.f;
}
static __device__ __forceinline__ unsigned short f2bf(float f) {
  union { float f; unsigned int i; } x; x.f = f;
  unsigned int u = x.i;
  unsigned int rnd = ((u >> 16) & 1u) + 0x7fffu;  // round-to-nearest-even
  return (unsigned short)((u + rnd) >> 16);
}

// ---------------- k0: bias[h][n*98+m] = table[rel[n*98+m]][h] ----------------
__global__ void k0_bias(const float* __restrict__ table,
                        const int* __restrict__ rel,
                        float* __restrict__ biasF) {
  int idx = blockIdx.x * 256 + threadIdx.x;
  if (idx >= HEADS * NN) return;
  int h = idx / NN, nm = idx - h * NN;
  biasF[idx] = table[(size_t)rel[nm] * HEADS + h];
}

// 4x4 register-tile fp32 microkernel over bf16 transposed LDS tiles.
static __device__ __forceinline__ void mm_tile(const unsigned short* xt,
                                               const unsigned short* wt,
                                               int trr, int tcc,
                                               float acc[4][4]) {
#pragma unroll 4
  for (int kk = 0; kk < 128; ++kk) {
    uint2 av = *(const uint2*)(xt + kk * XPAD + trr);  // rows trr..trr+3 (broadcast)
    uint2 bv = *(const uint2*)(wt + kk * WPAD + tcc);  // cols tcc..tcc+3 (2-way max)
    float a0 = lo2f(av.x), a1 = hi2f(av.x), a2 = lo2f(av.y), a3 = hi2f(av.y);
    float b0 = lo2f(bv.x), b1 = hi2f(bv.x), b2 = lo2f(bv.y), b3 = hi2f(bv.y);
    acc[0][0] += a0 * b0; acc[0][1] += a0 * b1; acc[0][2] += a0 * b2; acc[0][3] += a0 * b3;
    acc[1][0] += a1 * b0; acc[1][1] += a1 * b1; acc[1][2] += a1 * b2; acc[1][3] += a1 * b3;
    acc[2][0] += a2 * b0; acc[2][1] += a2 * b1; acc[2][2] += a2 * b2; acc[2][3] += a2 * b3;
    acc[3][0] += a3 * b0; acc[3][1] += a3 * b1; acc[3][2] += a3 * b2; acc[3][3] += a3 * b3;
  }
}

// ---------------- k1: QKV GEMM (M=200704, N=384 in 3 col-tiles, K=128) ------
__global__ __launch_bounds__(256) void k1_qkv(const float* __restrict__ x,
                                              const float* __restrict__ w,
                                              const float* __restrict__ wb,
                                              unsigned short* __restrict__ q,
                                              unsigned short* __restrict__ k,
                                              unsigned short* __restrict__ v) {
  __shared__ unsigned short xt[128 * XPAD];  // [kk][row]
  __shared__ unsigned short wt[128 * WPAD];  // [kk][col]
  const int t = threadIdx.x;
  const int r0 = blockIdx.x * TR;
  const int ct = blockIdx.y;  // 0=q, 1=k, 2=v
  const int c0 = ct << 7;

#pragma unroll
  for (int i = 0; i < 16; ++i) {  // x tile 32x128 fp32 -> bf16 transposed
    int idx = t + (i << 8);
    int row = idx >> 7, kk = idx & 127;
    xt[kk * XPAD + row] = f2bf(x[(size_t)(r0 + row) * 128 + kk]);
  }
#pragma unroll
  for (int i = 0; i < 64; ++i) {  // w tile 128x128 fp32 -> bf16 transposed
    int idx = t + (i << 8);
    int c = idx >> 7, kk = idx & 127;
    wt[kk * WPAD + c] = f2bf(w[(size_t)(c0 + c) * 128 + kk]);
  }
  __syncthreads();

  const int trr = (t >> 5) << 2;  // 0..28
  const int tcc = (t & 31) << 2;  // 0..124
  float acc[4][4] = {};
  mm_tile(xt, wt, trr, tcc, acc);

  unsigned short* dst = (ct == 0) ? q : ((ct == 1) ? k : v);
  const float sc = (ct == 0) ? SCALE : 1.0f;
  float bias[4];
#pragma unroll
  for (int j = 0; j < 4; ++j) bias[j] = wb[c0 + tcc + j];
#pragma unroll
  for (int i = 0; i < 4; ++i) {
    int R = r0 + trr + i;
    int b = R / NTOK, n = R - b * NTOK;
#pragma unroll
    for (int j = 0; j < 4; ++j) {
      int c = tcc + j;
      int h = c >> 5, d = c & 31;
      float val = (acc[i][j] + bias[j]) * sc;
      dst[((size_t)(b * HEADS + h) * NTOK + n) * HD + d] = f2bf(val);
    }
  }
}

// ---------------- k2: attention per (window, head) ---------------------------
__global__ __launch_bounds__(256) void k2_attn(const unsigned short* __restrict__ qg,
                                               const unsigned short* __restrict__ kg,
                                               const unsigned short* __restrict__ vg,
                                               const float* __restrict__ mask,
                                               const float* __restrict__ biasF,
                                               unsigned short* __restrict__ og) {
  __shared__ unsigned short sQ[NTOK * QPAD];
  __shared__ unsigned short sK[NTOK * QPAD];
  __shared__ unsigned short sV[NTOK * QPAD];
  __shared__ float sS[NTOK * NTOK];
  const int t = threadIdx.x;
  const int bh = blockIdx.x;
  const int bw = bh >> 2, h = bh & 3;
  const size_t base = (size_t)bh * (NTOK * HD);

  for (int idx = t; idx < NTOK * HD / 2; idx += 256) {
    int n = idx >> 4, dp = idx & 15;
    *(unsigned int*)&sQ[n * QPAD + dp * 2] = *(const unsigned int*)&qg[base + n * HD + dp * 2];
  }
  for (int idx = t; idx < NTOK * HD / 2; idx += 256) {
    int n = idx >> 4, dp = idx & 15;
    *(unsigned int*)&sK[n * QPAD + dp * 2] = *(const unsigned int*)&kg[base + n * HD + dp * 2];
  }
  for (int idx = t; idx < NTOK * HD / 2; idx += 256) {
    int n = idx >> 4, dp = idx & 15;
    *(unsigned int*)&sV[n * QPAD + dp * 2] = *(const unsigned int*)&vg[base + n * HD + dp * 2];
  }
  __syncthreads();

  const float* maskp = mask + (size_t)(bw & 255) * NN;
  const float* biasp = biasF + (size_t)h * NN;

  if (t < 196) {  // scores: thread = (row, half of m-range); q row in registers
    const int n = t >> 1;
    const int m0 = (t & 1) * 49;
    float qr[32];
#pragma unroll
    for (int dp = 0; dp < 16; ++dp) {
      unsigned int u = *(const unsigned int*)&sQ[n * QPAD + dp * 2];
      qr[dp * 2] = lo2f(u); qr[dp * 2 + 1] = hi2f(u);
    }
    for (int mm = 0; mm < 49; ++mm) {
      int m = m0 + mm;
      float s = 0.f;
#pragma unroll
      for (int dp = 0; dp < 16; ++dp) {
        unsigned int u = *(const unsigned int*)&sK[m * QPAD + dp * 2];
        s += qr[dp * 2] * lo2f(u) + qr[dp * 2 + 1] * hi2f(u);
      }
      sS[n * NTOK + m] = s + biasp[n * NTOK + m] + maskp[n * NTOK + m];
    }
  }
  __syncthreads();

  if (t < NTOK) {  // softmax, one thread per row
    float mx = -3.0e38f;
    for (int m = 0; m < NTOK; ++m) mx = fmaxf(mx, sS[t * NTOK + m]);
    float sum = 0.f;
    for (int m = 0; m < NTOK; ++m) {
      float e = __expf(sS[t * NTOK + m] - mx);
      sS[t * NTOK + m] = e; sum += e;
    }
    float r = 1.0f / sum;
    for (int m = 0; m < NTOK; ++m) sS[t * NTOK + m] *= r;
  }
  __syncthreads();

  if (t < 196) {  // PV: thread = (row, 16-col half)
    const int n = t >> 1;
    const int d0 = (t & 1) * 16;
    float acc[16] = {};
    for (int m = 0; m < NTOK; ++m) {
      float p = sS[n * NTOK + m];
#pragma unroll
      for (int dp = 0; dp < 8; ++dp) {
        unsigned int u = *(const unsigned int*)&sV[m * QPAD + d0 + dp * 2];
        acc[dp * 2]     += p * lo2f(u);
        acc[dp * 2 + 1] += p * hi2f(u);
      }
    }
    size_t ob = ((size_t)(bw * NTOK + n)) * 128 + h * HD + d0;
#pragma unroll
    for (int j4 = 0; j4 < 4; ++j4) {
      ushort4 pk;
      pk.x = f2bf(acc[j4 * 4 + 0]); pk.y = f2bf(acc[j4 * 4 + 1]);
      pk.z = f2bf(acc[j4 * 4 + 2]); pk.w = f2bf(acc[j4 * 4 + 3]);
      *(ushort4*)&og[ob + j4 * 4] = pk;
    }
  }
}

// ---------------- k3: proj GEMM (M=200704, N=128, K=128) ---------------------
__global__ __launch_bounds__(256) void k3_proj(const unsigned short* __restrict__ og,
                                               const float* __restrict__ w,
                                               const float* __restrict__ pb,
                                               float* __restrict__ out) {
  __shared__ unsigned short ot[128 * XPAD];
  __shared__ unsigned short wt[128 * WPAD];
  const int t = threadIdx.x;
  const int r0 = blockIdx.x * TR;

#pragma unroll
  for (int i = 0; i < 8; ++i) {  // o tile 32x128 bf16, transposed into LDS
    int idx = t + (i << 8);
    int row = idx >> 6, kp = idx & 63;
    unsigned int u = *(const unsigned int*)&og[(size_t)(r0 + row) * 128 + kp * 2];
    ot[(kp * 2) * XPAD + row]     = (unsigned short)(u & 0xffffu);
    ot[(kp * 2 + 1) * XPAD + row] = (unsigned short)(u >> 16);
  }
#pragma unroll
  for (int i = 0; i < 64; ++i) {
    int idx = t + (i << 8);
    int c = idx >> 7, kk = idx & 127;
    wt[kk * WPAD + c] = f2bf(w[(size_t)c * 128 + kk]);
  }
  __syncthreads();

  const int trr = (t >> 5) << 2;
  const int tcc = (t & 31) << 2;
  float acc[4][4] = {};
  mm_tile(ot, wt, trr, tcc, acc);

#pragma unroll
  for (int i = 0; i < 4; ++i) {
    size_t R = (size_t)(r0 + trr + i);
    float4 o4;
    o4.x = acc[i][0] + pb[tcc + 0];
    o4.y = acc[i][1] + pb[tcc + 1];
    o4.z = acc[i][2] + pb[tcc + 2];
    o4.w = acc[i][3] + pb[tcc + 3];
    *(float4*)&out[R * 128 + tcc] = o4;
  }
}

extern "C" void kernel_launch(void* const* d_in, const int* in_sizes, int n_in,
                              void* d_out, int out_size, void* d_ws, size_t ws_size,
                              hipStream_t stream) {
  (void)in_sizes; (void)n_in; (void)out_size; (void)ws_size;
  const float* x      = (const float*)d_in[0];
  const float* mask   = (const float*)d_in[1];
  const float* qkv_w  = (const float*)d_in[2];
  const float* qkv_b  = (const float*)d_in[3];
  const float* proj_w = (const float*)d_in[4];
  const float* proj_b = (const float*)d_in[5];
  const float* table  = (const float*)d_in[6];
  const int*   rel    = (const int*)d_in[7];
  float* out = (float*)d_out;

  const size_t QS = (size_t)2048 * HEADS * NTOK * HD;  // 25,690,112 elems
  unsigned short* q = (unsigned short*)d_ws;
  unsigned short* k = q + QS;
  unsigned short* v = k + QS;
  unsigned short* o = v + QS;  // [b][n][128] bf16
  float* biasF = (float*)(o + QS);  // [4][98*98] fp32

  k0_bias<<<(HEADS * NN + 255) / 256, 256, 0, stream>>>(table, rel, biasF);
  k1_qkv<<<dim3(200704 / TR, 3), 256, 0, stream>>>(x, qkv_w, qkv_b, q, k, v);
  k2_attn<<<2048 * HEADS, 256, 0, stream>>>(q, k, v, mask, biasF, o);
  k3_proj<<<200704 / TR, 256, 0, stream>>>(o, proj_w, proj_b, out);
}

// Round 2
// 517.898 us; speedup vs baseline: 2.2608x; 2.2608x over previous
//
#include <hip/hip_runtime.h>
#include <hip/hip_bf16.h>

// WindowAttention3D on MFMA (round 1).
// B=2048 windows, N=98 (pad 112), C=128, H=4, hd=32, mask windows=256.
//   k0: convert qkv_w/proj_w -> bf16, gather bias[h][n][m]
//   k1: qkv GEMM via mfma_f32_16x16x32_bf16 -> q*scale,k,v bf16 [b][h][98][32]
//   k2: per (b,h): S=QK^T (MFMA) + bias + mask, softmax (shuffle), PV (MFMA)
//   k3: proj GEMM (MFMA) -> fp32 out
// ws: q,k,v,o (4 x 25690112 bf16) + wqb(49152) + wpb(16384) bf16 + biasF(38416 f32)

#define NTOK 98
#define NN (NTOK * NTOK)
#define SCALE 0.17677669529663687f

typedef short bf16x8 __attribute__((ext_vector_type(8)));
typedef float f32x4 __attribute__((ext_vector_type(4)));
#define MFMA(a, b, c) __builtin_amdgcn_mfma_f32_16x16x32_bf16(a, b, c, 0, 0, 0)

static __device__ __forceinline__ unsigned short f2bf(float f) {
  union { float f; unsigned int i; } x; x.f = f;
  unsigned int u = x.i;
  unsigned int rnd = ((u >> 16) & 1u) + 0x7fffu;  // RNE
  return (unsigned short)((u + rnd) >> 16);
}

// ---------------- k0: weight converts + bias gather --------------------------
__global__ void k0_pre(const float* __restrict__ table, const int* __restrict__ rel,
                       const float* __restrict__ qkv_w, const float* __restrict__ proj_w,
                       unsigned short* __restrict__ wqb, unsigned short* __restrict__ wpb,
                       float* __restrict__ biasF) {
  int idx = blockIdx.x * 256 + threadIdx.x;
  if (idx < 49152) {
    wqb[idx] = f2bf(qkv_w[idx]);
  } else if (idx < 65536) {
    wpb[idx - 49152] = f2bf(proj_w[idx - 49152]);
  } else if (idx < 65536 + 4 * NN) {
    int j = idx - 65536;
    int h = j / NN, nm = j - h * NN;
    biasF[j] = table[(size_t)rel[nm] * 4 + h];
  }
}

// ---------------- k1: QKV GEMM, 64 rows x 384 cols per block -----------------
__global__ __launch_bounds__(256) void k1_qkv(const float* __restrict__ x,
                                              const unsigned short* __restrict__ wqb,
                                              const float* __restrict__ qkv_b,
                                              unsigned short* __restrict__ q,
                                              unsigned short* __restrict__ k,
                                              unsigned short* __restrict__ v) {
  __shared__ unsigned short xt[64 * 136];   // [row][k], stride 136 (+8 pad, 16B-aligned)
  __shared__ unsigned short wt[128 * 136];  // [col][k]
  const int t = threadIdx.x;
  const int r0 = blockIdx.x * 64;
  const int wv = t >> 6, lane = t & 63, L15 = lane & 15, quad = lane >> 4;

#pragma unroll
  for (int i = 0; i < 32; ++i) {  // x 64x128 fp32 -> bf16 LDS
    int idx = t + (i << 8);
    int row = idx >> 7, kk = idx & 127;
    xt[row * 136 + kk] = f2bf(x[(size_t)(r0 + row) * 128 + kk]);
  }

  bf16x8 af[4];
  bool afLoaded = false;

  for (int g = 0; g < 3; ++g) {
    if (g) __syncthreads();  // previous group's wt reads done
#pragma unroll
    for (int i = 0; i < 32; ++i) {  // w tile 128x128 bf16 -> LDS (uint copies)
      int idx = t + (i << 8);
      int c = idx >> 6, kp = idx & 63;
      *(unsigned int*)&wt[c * 136 + kp * 2] =
          ((const unsigned int*)wqb)[g * 8192 + idx];
    }
    __syncthreads();
    if (!afLoaded) {
      afLoaded = true;
#pragma unroll
      for (int kt = 0; kt < 4; ++kt)
        af[kt] = *(const bf16x8*)&xt[(wv * 16 + L15) * 136 + kt * 32 + quad * 8];
    }

    f32x4 acc[8];
#pragma unroll
    for (int nt = 0; nt < 8; ++nt) {
      f32x4 a = {0.f, 0.f, 0.f, 0.f};
#pragma unroll
      for (int kt = 0; kt < 4; ++kt) {
        bf16x8 bf_ = *(const bf16x8*)&wt[(nt * 16 + L15) * 136 + kt * 32 + quad * 8];
        a = MFMA(af[kt], bf_, a);
      }
      acc[nt] = a;
    }

    unsigned short* dst = (g == 0) ? q : ((g == 1) ? k : v);
    const float sc = (g == 0) ? SCALE : 1.0f;
    float bias[8];
#pragma unroll
    for (int nt = 0; nt < 8; ++nt) bias[nt] = qkv_b[g * 128 + nt * 16 + L15];
#pragma unroll
    for (int reg = 0; reg < 4; ++reg) {
      int R = r0 + wv * 16 + quad * 4 + reg;
      int b = R / NTOK, n = R - b * NTOK;
      size_t base0 = ((size_t)b * 4 * NTOK + n) * 32;
#pragma unroll
      for (int nt = 0; nt < 8; ++nt) {
        int h = nt >> 1, dd = ((nt & 1) << 4) + L15;
        float val = (acc[nt][reg] + bias[nt]) * sc;
        dst[base0 + (size_t)h * (NTOK * 32) + dd] = f2bf(val);
      }
    }
  }
}

// ---------------- k2: MFMA attention, one block per (window, head) -----------
__global__ __launch_bounds__(256) void k2_attn(const unsigned short* __restrict__ qg,
                                               const unsigned short* __restrict__ kg,
                                               const unsigned short* __restrict__ vg,
                                               const float* __restrict__ mask,
                                               const float* __restrict__ biasF,
                                               unsigned short* __restrict__ og) {
  __shared__ unsigned short sK[112 * 40];        // [n][k<32], rows 98..111 zero
  __shared__ unsigned short sVt[32 * 136];       // [d][n], cols 98..127 zero
  __shared__ unsigned short sP[4 * 16 * 136];    // per-wave P strip [m][n]
  const int t = threadIdx.x;
  const int bh = blockIdx.x, bw = bh >> 2, h = bh & 3;
  const size_t base = (size_t)bh * (NTOK * 32);
  const int wv = t >> 6, lane = t & 63, L15 = lane & 15, quad = lane >> 4;

  for (int i = t; i < 2240; i += 256) ((unsigned int*)sK)[i] = 0;
  for (int i = t; i < 2176; i += 256) ((unsigned int*)sVt)[i] = 0;
  for (int i = t; i < 4352; i += 256) ((unsigned int*)sP)[i] = 0;
  __syncthreads();
  for (int i = t; i < 98 * 16; i += 256) {  // K rows, uint copies
    int row = i >> 4, kp = i & 15;
    *(unsigned int*)&sK[row * 40 + kp * 2] =
        ((const unsigned int*)kg)[(base >> 1) + row * 16 + kp];
  }
  for (int i = t; i < 98 * 32; i += 256) {  // V transpose (scalar)
    int n = i >> 5, d = i & 31;
    sVt[d * 136 + n] = vg[base + i];
  }
  __syncthreads();

  const float* maskp = mask + (size_t)(bw & 255) * NN;
  const float* biasp = biasF + (size_t)h * NN;
  unsigned short* myP = sP + wv * (16 * 136);

  for (int mt = wv; mt < 7; mt += 4) {
    // S = Q K^T  (Q A-frag straight from global; rows >=98 read junk, discarded)
    bf16x8 aq = *(const bf16x8*)&qg[base + (size_t)(mt * 16 + L15) * 32 + quad * 8];
    f32x4 s[7];
#pragma unroll
    for (int nt = 0; nt < 7; ++nt) {
      bf16x8 bk = *(const bf16x8*)&sK[(nt * 16 + L15) * 40 + quad * 8];
      f32x4 z = {0.f, 0.f, 0.f, 0.f};
      s[nt] = MFMA(aq, bk, z);
    }
    // bias + mask + row softmax (row = quad*4+reg, cols across 16 lanes x 7 frags)
#pragma unroll
    for (int reg = 0; reg < 4; ++reg) {
      int row = mt * 16 + quad * 4 + reg;
      int rm = row < NTOK ? row : NTOK - 1;
      float mx = -3.0e38f;
#pragma unroll
      for (int nt = 0; nt < 7; ++nt) {
        int col = nt * 16 + L15;
        int cm = col < NTOK ? col : NTOK - 1;
        float val = s[nt][reg] + biasp[rm * NTOK + cm] + maskp[rm * NTOK + cm];
        if (col >= NTOK) val = -1.0e30f;
        s[nt][reg] = val;
        mx = fmaxf(mx, val);
      }
#pragma unroll
      for (int d = 1; d < 16; d <<= 1) mx = fmaxf(mx, __shfl_xor(mx, d, 64));
      float sum = 0.f;
#pragma unroll
      for (int nt = 0; nt < 7; ++nt) {
        float e = __expf(s[nt][reg] - mx);
        s[nt][reg] = e; sum += e;
      }
#pragma unroll
      for (int d = 1; d < 16; d <<= 1) sum += __shfl_xor(sum, d, 64);
      float rs = 1.0f / sum;
#pragma unroll
      for (int nt = 0; nt < 7; ++nt)
        myP[(quad * 4 + reg) * 136 + nt * 16 + L15] = f2bf(s[nt][reg] * rs);
    }
    // O = P V   (P via LDS round-trip C/D->A layout; cols 112..127 stay zero)
    f32x4 o0 = {0.f, 0.f, 0.f, 0.f}, o1 = {0.f, 0.f, 0.f, 0.f};
#pragma unroll
    for (int kt = 0; kt < 4; ++kt) {
      bf16x8 ap  = *(const bf16x8*)&myP[L15 * 136 + kt * 32 + quad * 8];
      bf16x8 bv0 = *(const bf16x8*)&sVt[L15 * 136 + kt * 32 + quad * 8];
      bf16x8 bv1 = *(const bf16x8*)&sVt[(16 + L15) * 136 + kt * 32 + quad * 8];
      o0 = MFMA(ap, bv0, o0);
      o1 = MFMA(ap, bv1, o1);
    }
#pragma unroll
    for (int reg = 0; reg < 4; ++reg) {
      int n = mt * 16 + quad * 4 + reg;
      if (n < NTOK) {
        size_t ob = ((size_t)bw * NTOK + n) * 128 + h * 32;
        og[ob + L15]      = f2bf(o0[reg]);
        og[ob + 16 + L15] = f2bf(o1[reg]);
      }
    }
  }
}

// ---------------- k3: proj GEMM, 64 rows x 128 cols per block ----------------
__global__ __launch_bounds__(256) void k3_proj(const unsigned short* __restrict__ og,
                                               const unsigned short* __restrict__ wpb,
                                               const float* __restrict__ pb,
                                               float* __restrict__ out) {
  __shared__ unsigned short ot[64 * 136];
  __shared__ unsigned short wt[128 * 136];
  const int t = threadIdx.x;
  const int r0 = blockIdx.x * 64;
  const int wv = t >> 6, lane = t & 63, L15 = lane & 15, quad = lane >> 4;

#pragma unroll
  for (int i = 0; i < 16; ++i) {  // o tile 64x128 bf16 (uint copies)
    int idx = t + (i << 8);
    int row = idx >> 6, kp = idx & 63;
    *(unsigned int*)&ot[row * 136 + kp * 2] =
        ((const unsigned int*)og)[(size_t)(r0 + row) * 64 + kp];
  }
#pragma unroll
  for (int i = 0; i < 32; ++i) {  // w 128x128 bf16
    int idx = t + (i << 8);
    int c = idx >> 6, kp = idx & 63;
    *(unsigned int*)&wt[c * 136 + kp * 2] = ((const unsigned int*)wpb)[idx];
  }
  __syncthreads();

  bf16x8 af[4];
#pragma unroll
  for (int kt = 0; kt < 4; ++kt)
    af[kt] = *(const bf16x8*)&ot[(wv * 16 + L15) * 136 + kt * 32 + quad * 8];

  f32x4 acc[8];
#pragma unroll
  for (int nt = 0; nt < 8; ++nt) {
    f32x4 a = {0.f, 0.f, 0.f, 0.f};
#pragma unroll
    for (int kt = 0; kt < 4; ++kt) {
      bf16x8 bf_ = *(const bf16x8*)&wt[(nt * 16 + L15) * 136 + kt * 32 + quad * 8];
      a = MFMA(af[kt], bf_, a);
    }
    acc[nt] = a;
  }

  float bias[8];
#pragma unroll
  for (int nt = 0; nt < 8; ++nt) bias[nt] = pb[nt * 16 + L15];
#pragma unroll
  for (int reg = 0; reg < 4; ++reg) {
    size_t R = (size_t)(r0 + wv * 16 + quad * 4 + reg);
#pragma unroll
    for (int nt = 0; nt < 8; ++nt)
      out[R * 128 + nt * 16 + L15] = acc[nt][reg] + bias[nt];
  }
}

extern "C" void kernel_launch(void* const* d_in, const int* in_sizes, int n_in,
                              void* d_out, int out_size, void* d_ws, size_t ws_size,
                              hipStream_t stream) {
  (void)in_sizes; (void)n_in; (void)out_size; (void)ws_size;
  const float* x      = (const float*)d_in[0];
  const float* mask   = (const float*)d_in[1];
  const float* qkv_w  = (const float*)d_in[2];
  const float* qkv_b  = (const float*)d_in[3];
  const float* proj_w = (const float*)d_in[4];
  const float* proj_b = (const float*)d_in[5];
  const float* table  = (const float*)d_in[6];
  const int*   rel    = (const int*)d_in[7];
  float* out = (float*)d_out;

  const size_t QS = (size_t)2048 * 4 * NTOK * 32;  // 25,690,112
  unsigned short* q   = (unsigned short*)d_ws;
  unsigned short* k   = q + QS;
  unsigned short* v   = k + QS;
  unsigned short* o   = v + QS;  // [b][n][128] bf16
  unsigned short* wqb = o + QS;
  unsigned short* wpb = wqb + 49152;
  float* biasF = (float*)(wpb + 16384);

  k0_pre<<<(65536 + 4 * NN + 255) / 256, 256, 0, stream>>>(table, rel, qkv_w, proj_w,
                                                           wqb, wpb, biasF);
  k1_qkv<<<200704 / 64, 256, 0, stream>>>(x, wqb, qkv_b, q, k, v);
  k2_attn<<<2048 * 4, 256, 0, stream>>>(q, k, v, mask, biasF, o);
  k3_proj<<<200704 / 64, 256, 0, stream>>>(o, wpb, proj_b, out);
}

// Round 3
// 378.391 us; speedup vs baseline: 3.0943x; 1.3687x over previous
//
#include <hip/hip_runtime.h>
#include <hip/hip_bf16.h>

// WindowAttention3D MFMA round 2.
// k0 : qkv_w/proj_w -> bf16
// k0b: bm[wmod][h][strip][lane][32] = bf16(bias+mask) pre-swizzled into the
//      16x16x32 MFMA C/D fragment order, pads = -1e30.  Lives in d_out
//      (scratch until k3 overwrites; stream order serializes k2 -> k3).
// k1 : qkv GEMM (MFMA) -> q*scale,k,v bf16 [b][h][98][32]
// k2 : per (b,h): S=QK^T +bm, softmax (16-lane shuffles), PV -> o bf16 [b][n][128]
// k3 : proj GEMM (MFMA) -> fp32 out
// ws: q,k,v,o (4 x 25,690,112 bf16) + wqb(49152) + wpb(16384) = 205,651,968 B

#define NTOK 98
#define NN (NTOK * NTOK)
#define SCALE 0.17677669529663687f

typedef short bf16x8 __attribute__((ext_vector_type(8)));
typedef float f32x4 __attribute__((ext_vector_type(4)));
#define MFMA(a, b, c) __builtin_amdgcn_mfma_f32_16x16x32_bf16(a, b, c, 0, 0, 0)

static __device__ __forceinline__ unsigned short f2bf(float f) {
  union { float f; unsigned int i; } x; x.f = f;
  unsigned int u = x.i;
  unsigned int rnd = ((u >> 16) & 1u) + 0x7fffu;  // RNE
  return (unsigned short)((u + rnd) >> 16);
}
static __device__ __forceinline__ float bf2f(short s) {
  union { unsigned int i; float f; } x;
  x.i = ((unsigned int)(unsigned short)s) << 16;
  return x.f;
}

// ---------------- k0: weight converts --------------------------------------
__global__ void k0_w(const float* __restrict__ qkv_w, const float* __restrict__ proj_w,
                     unsigned short* __restrict__ wqb, unsigned short* __restrict__ wpb) {
  int idx = blockIdx.x * 256 + threadIdx.x;
  if (idx < 49152) wqb[idx] = f2bf(qkv_w[idx]);
  else wpb[idx - 49152] = f2bf(proj_w[idx - 49152]);
}

// ---------------- k0b: fused bias+mask in fragment order ---------------------
// grid (1024, 7): x = wmod*4+h, y = strip. thread t: lane=t>>2, reg=t&3.
__global__ void k0b_bm(const float* __restrict__ table, const int* __restrict__ rel,
                       const float* __restrict__ mask, unsigned short* __restrict__ bm) {
  const int wmodh = blockIdx.x, mt = blockIdx.y;
  const int wmod = wmodh >> 2, h = wmodh & 3;
  const int t = threadIdx.x;
  const int lane = t >> 2, reg = t & 3;
  const int quad = lane >> 4, L15 = lane & 15;
  const int row = mt * 16 + quad * 4 + reg;
  bf16x8 v8;
#pragma unroll
  for (int nt = 0; nt < 8; ++nt) {
    float v = -1.0e30f;
    int col = nt * 16 + L15;
    if (nt < 7 && row < NTOK && col < NTOK) {
      int nm = row * NTOK + col;
      v = table[rel[nm] * 4 + h] + mask[(size_t)wmod * NN + nm];
    }
    v8[nt] = (short)f2bf(v);
  }
  *(bf16x8*)&bm[(((size_t)wmodh * 7 + mt) << 11) + (lane << 5) + (reg << 3)] = v8;
}

// ---------------- k1: QKV GEMM, 64 rows x 384 cols per block -----------------
__global__ __launch_bounds__(256) void k1_qkv(const float* __restrict__ x,
                                              const unsigned short* __restrict__ wqb,
                                              const float* __restrict__ qkv_b,
                                              unsigned short* __restrict__ q,
                                              unsigned short* __restrict__ k,
                                              unsigned short* __restrict__ v) {
  __shared__ unsigned short xt[64 * 136];   // [row][k], stride 136 (16B-aligned rows)
  __shared__ unsigned short wt[128 * 136];  // [col][k]
  const int t = threadIdx.x;
  const int r0 = blockIdx.x * 64;
  const int wv = t >> 6, lane = t & 63, L15 = lane & 15, quad = lane >> 4;

#pragma unroll
  for (int i = 0; i < 8; ++i) {  // x 64x128 fp32 -> bf16 (float4 -> ushort4)
    int idx = t + (i << 8);
    int row = idx >> 5, c4 = idx & 31;
    float4 xv = *(const float4*)&x[(size_t)(r0 + row) * 128 + c4 * 4];
    ushort4 pk; pk.x = f2bf(xv.x); pk.y = f2bf(xv.y); pk.z = f2bf(xv.z); pk.w = f2bf(xv.w);
    *(ushort4*)&xt[row * 136 + c4 * 4] = pk;
  }

  bf16x8 af[4];
  bool afLoaded = false;

  for (int g = 0; g < 3; ++g) {
    if (g) __syncthreads();
#pragma unroll
    for (int i = 0; i < 8; ++i) {  // w tile 128x128 bf16 via uint4
      int idx = t + (i << 8);
      int c = idx >> 4, kq = idx & 15;
      *(uint4*)&wt[c * 136 + kq * 8] = ((const uint4*)wqb)[g * 2048 + idx];
    }
    __syncthreads();
    if (!afLoaded) {
      afLoaded = true;
#pragma unroll
      for (int kt = 0; kt < 4; ++kt)
        af[kt] = *(const bf16x8*)&xt[(wv * 16 + L15) * 136 + kt * 32 + quad * 8];
    }

    f32x4 acc[8];
#pragma unroll
    for (int nt = 0; nt < 8; ++nt) {
      f32x4 a = {0.f, 0.f, 0.f, 0.f};
#pragma unroll
      for (int kt = 0; kt < 4; ++kt) {
        bf16x8 bf_ = *(const bf16x8*)&wt[(nt * 16 + L15) * 136 + kt * 32 + quad * 8];
        a = MFMA(af[kt], bf_, a);
      }
      acc[nt] = a;
    }

    unsigned short* dst = (g == 0) ? q : ((g == 1) ? k : v);
    const float sc = (g == 0) ? SCALE : 1.0f;
    float bias[8];
#pragma unroll
    for (int nt = 0; nt < 8; ++nt) bias[nt] = qkv_b[g * 128 + nt * 16 + L15];
#pragma unroll
    for (int reg = 0; reg < 4; ++reg) {
      int R = r0 + wv * 16 + quad * 4 + reg;
      int b = R / NTOK, n = R - b * NTOK;
      size_t base0 = ((size_t)b * 4 * NTOK + n) * 32;
#pragma unroll
      for (int nt = 0; nt < 8; ++nt) {
        int h = nt >> 1, dd = ((nt & 1) << 4) + L15;
        float val = (acc[nt][reg] + bias[nt]) * sc;
        dst[base0 + (size_t)h * (NTOK * 32) + dd] = f2bf(val);
      }
    }
  }
}

// ---------------- k2: MFMA attention, one block per (window, head) -----------
__global__ __launch_bounds__(256) void k2_attn(const unsigned short* __restrict__ qg,
                                               const unsigned short* __restrict__ kg,
                                               const unsigned short* __restrict__ vg,
                                               const unsigned short* __restrict__ bm,
                                               unsigned short* __restrict__ og) {
  __shared__ unsigned short sK[112 * 40];      // [n][k<32], rows 98..111 zeroed
  __shared__ unsigned short sVt[32 * 136];     // [d][n] (cols >=98 garbage: P there = 0)
  __shared__ unsigned short sP[4 * 16 * 136];  // per-wave P strip [m][n]
  const int t = threadIdx.x;
  const int bh = blockIdx.x, bw = bh >> 2, h = bh & 3;
  const int wmodh = ((bw & 255) << 2) + h;
  const size_t base = (size_t)bh * (NTOK * 32);
  const int wv = t >> 6, lane = t & 63, L15 = lane & 15, quad = lane >> 4;
  unsigned short* myP = sP + wv * (16 * 136);

  for (int i = t; i < 2240; i += 256) ((unsigned int*)sK)[i] = 0;  // incl. pad rows
  for (int j = lane; j < 128; j += 64) {  // myP cols 112..127 (never written later)
    int r = j >> 3, cp = j & 7;
    *(unsigned int*)&myP[r * 136 + 112 + cp * 2] = 0;
  }
  __syncthreads();
  for (int i = t; i < 392; i += 256) {  // K rows via uint4
    int row = i >> 2, kq = i & 3;
    *(uint4*)&sK[row * 40 + kq * 8] = ((const uint4*)kg)[(size_t)bh * 392 + i];
  }
  for (int i = t; i < 3136; i += 256) {  // V transpose (scalar)
    int n = i >> 5, d = i & 31;
    sVt[d * 136 + n] = vg[base + i];
  }
  __syncthreads();

  auto strip = [&](int mt) {
    const unsigned short* bmp = bm + (((size_t)wmodh * 7 + mt) << 11) + (lane << 5);
    bf16x8 bmv[4];
#pragma unroll
    for (int reg = 0; reg < 4; ++reg) bmv[reg] = *(const bf16x8*)&bmp[reg << 3];
    bf16x8 aq = *(const bf16x8*)&qg[base + (size_t)(mt * 16 + L15) * 32 + quad * 8];
    f32x4 s[7];
#pragma unroll
    for (int nt = 0; nt < 7; ++nt) {
      bf16x8 bk = *(const bf16x8*)&sK[(nt * 16 + L15) * 40 + quad * 8];
      f32x4 z = {0.f, 0.f, 0.f, 0.f};
      s[nt] = MFMA(aq, bk, z);
    }
#pragma unroll
    for (int reg = 0; reg < 4; ++reg) {
      float mx = -3.0e38f;
#pragma unroll
      for (int nt = 0; nt < 7; ++nt) {
        float val = s[nt][reg] + bf2f(bmv[reg][nt]);
        s[nt][reg] = val;
        mx = fmaxf(mx, val);
      }
#pragma unroll
      for (int d = 1; d < 16; d <<= 1) mx = fmaxf(mx, __shfl_xor(mx, d, 64));
      float sum = 0.f;
#pragma unroll
      for (int nt = 0; nt < 7; ++nt) {
        float e = __expf(s[nt][reg] - mx);
        s[nt][reg] = e; sum += e;
      }
#pragma unroll
      for (int d = 1; d < 16; d <<= 1) sum += __shfl_xor(sum, d, 64);
      float rs = 1.0f / sum;
#pragma unroll
      for (int nt = 0; nt < 7; ++nt)
        myP[(quad * 4 + reg) * 136 + nt * 16 + L15] = f2bf(s[nt][reg] * rs);
    }
    f32x4 o0 = {0.f, 0.f, 0.f, 0.f}, o1 = {0.f, 0.f, 0.f, 0.f};
#pragma unroll
    for (int kt = 0; kt < 4; ++kt) {
      bf16x8 ap  = *(const bf16x8*)&myP[L15 * 136 + kt * 32 + quad * 8];
      bf16x8 bv0 = *(const bf16x8*)&sVt[L15 * 136 + kt * 32 + quad * 8];
      bf16x8 bv1 = *(const bf16x8*)&sVt[(16 + L15) * 136 + kt * 32 + quad * 8];
      o0 = MFMA(ap, bv0, o0);
      o1 = MFMA(ap, bv1, o1);
    }
#pragma unroll
    for (int reg = 0; reg < 4; ++reg) {
      int n = mt * 16 + quad * 4 + reg;
      if (n < NTOK) {
        size_t ob = ((size_t)bw * NTOK + n) * 128 + h * 32;
        og[ob + L15]      = f2bf(o0[reg]);
        og[ob + 16 + L15] = f2bf(o1[reg]);
      }
    }
  };
  strip(wv * 2);
  if (wv < 3) strip(wv * 2 + 1);
}

// ---------------- k3: proj GEMM, 64 rows x 128 cols per block ----------------
__global__ __launch_bounds__(256) void k3_proj(const unsigned short* __restrict__ og,
                                               const unsigned short* __restrict__ wpb,
                                               const float* __restrict__ pb,
                                               float* __restrict__ out) {
  __shared__ unsigned short ot[64 * 136];
  __shared__ unsigned short wt[128 * 136];
  const int t = threadIdx.x;
  const int r0 = blockIdx.x * 64;
  const int wv = t >> 6, lane = t & 63, L15 = lane & 15, quad = lane >> 4;

#pragma unroll
  for (int i = 0; i < 4; ++i) {  // o tile 64x128 bf16 via uint4
    int idx = t + (i << 8);
    int row = idx >> 4, kq = idx & 15;
    *(uint4*)&ot[row * 136 + kq * 8] = ((const uint4*)og)[(size_t)(r0 + row) * 16 + kq];
  }
#pragma unroll
  for (int i = 0; i < 8; ++i) {  // w 128x128 bf16 via uint4
    int idx = t + (i << 8);
    int c = idx >> 4, kq = idx & 15;
    *(uint4*)&wt[c * 136 + kq * 8] = ((const uint4*)wpb)[idx];
  }
  __syncthreads();

  bf16x8 af[4];
#pragma unroll
  for (int kt = 0; kt < 4; ++kt)
    af[kt] = *(const bf16x8*)&ot[(wv * 16 + L15) * 136 + kt * 32 + quad * 8];

  f32x4 acc[8];
#pragma unroll
  for (int nt = 0; nt < 8; ++nt) {
    f32x4 a = {0.f, 0.f, 0.f, 0.f};
#pragma unroll
    for (int kt = 0; kt < 4; ++kt) {
      bf16x8 bf_ = *(const bf16x8*)&wt[(nt * 16 + L15) * 136 + kt * 32 + quad * 8];
      a = MFMA(af[kt], bf_, a);
    }
    acc[nt] = a;
  }

  float bias[8];
#pragma unroll
  for (int nt = 0; nt < 8; ++nt) bias[nt] = pb[nt * 16 + L15];
#pragma unroll
  for (int reg = 0; reg < 4; ++reg) {
    size_t R = (size_t)(r0 + wv * 16 + quad * 4 + reg);
#pragma unroll
    for (int nt = 0; nt < 8; ++nt)
      out[R * 128 + nt * 16 + L15] = acc[nt][reg] + bias[nt];
  }
}

extern "C" void kernel_launch(void* const* d_in, const int* in_sizes, int n_in,
                              void* d_out, int out_size, void* d_ws, size_t ws_size,
                              hipStream_t stream) {
  (void)in_sizes; (void)n_in; (void)out_size; (void)ws_size;
  const float* x      = (const float*)d_in[0];
  const float* mask   = (const float*)d_in[1];
  const float* qkv_w  = (const float*)d_in[2];
  const float* qkv_b  = (const float*)d_in[3];
  const float* proj_w = (const float*)d_in[4];
  const float* proj_b = (const float*)d_in[5];
  const float* table  = (const float*)d_in[6];
  const int*   rel    = (const int*)d_in[7];
  float* out = (float*)d_out;

  const size_t QS = (size_t)2048 * 4 * NTOK * 32;  // 25,690,112
  unsigned short* q   = (unsigned short*)d_ws;
  unsigned short* k   = q + QS;
  unsigned short* v   = k + QS;
  unsigned short* o   = v + QS;  // [b][n][128] bf16
  unsigned short* wqb = o + QS;
  unsigned short* wpb = wqb + 49152;
  unsigned short* bm  = (unsigned short*)d_out;  // scratch until k3 overwrites

  k0_w<<<256, 256, 0, stream>>>(qkv_w, proj_w, wqb, wpb);
  k0b_bm<<<dim3(1024, 7), 256, 0, stream>>>(table, rel, mask, bm);
  k1_qkv<<<200704 / 64, 256, 0, stream>>>(x, wqb, qkv_b, q, k, v);
  k2_attn<<<2048 * 4, 256, 0, stream>>>(q, k, v, bm, o);
  k3_proj<<<200704 / 64, 256, 0, stream>>>(o, wpb, proj_b, out);
}